// Round 1
// baseline (312.979 us; speedup 1.0000x reference)
//
#include <hip/hip_runtime.h>

// GridPoolingLayer: per-cell mean pooling where cells are rectangles defined
// by rising edges of h_mask (rows) and v_mask (cols). H=W=768, C=64, fp32.
//
// Structure:
//   seg_scan  : 2 blocks x 768 threads. Hillis-Steele scan of rising edges ->
//               segment [start,end) boundaries + segment count, into d_ws.
//   cell_pool : grid 385x385 (max segments/axis; fixed for graph capture),
//               one block per cell. 256 threads = 64 channels x 4 pixel groups.
//               Reduce rectangle -> mean -> broadcast to all pixels of cell.

#define GH 768
#define GW 768
#define GC 64
#define MAXSEG 385  // alternating mask 0,1,0,1,... gives 384 rising edges -> 385 segments

// d_ws layout (int32 words):
enum {
    OFF_ROWSTART = 0,
    OFF_ROWEND   = OFF_ROWSTART + MAXSEG,
    OFF_COLSTART = OFF_ROWEND + MAXSEG,
    OFF_COLEND   = OFF_COLSTART + MAXSEG,
    OFF_NROWS    = OFF_COLEND + MAXSEG,
    OFF_NCOLS    = OFF_NROWS + 1,
};

__global__ __launch_bounds__(768) void seg_scan(const int* __restrict__ h_mask,
                                                const int* __restrict__ v_mask,
                                                int* __restrict__ ws) {
    __shared__ int s[GH];
    const int i = threadIdx.x;
    const bool is_row = (blockIdx.x == 0);
    const int* m = is_row ? h_mask : v_mask;

    int mi = m[i];
    int rising = 0;
    if (i > 0) rising = (mi == 1 && m[i - 1] == 0) ? 1 : 0;  // rising[0] forced 0
    s[i] = rising;
    __syncthreads();

    // Hillis-Steele inclusive scan over 768 elements
    for (int off = 1; off < GH; off <<= 1) {
        int add = (i >= off) ? s[i - off] : 0;
        __syncthreads();
        s[i] += add;
        __syncthreads();
    }

    const int seg  = s[i];
    const int segL = (i == 0)      ? -1 : s[i - 1];
    const int segR = (i == GH - 1) ? -2 : s[i + 1];

    int* start = ws + (is_row ? OFF_ROWSTART : OFF_COLSTART);
    int* end   = ws + (is_row ? OFF_ROWEND   : OFF_COLEND);
    if (seg != segL) start[seg] = i;
    if (seg != segR) end[seg]   = i + 1;
    if (i == GH - 1) ws[is_row ? OFF_NROWS : OFF_NCOLS] = seg + 1;
}

__global__ __launch_bounds__(256) void cell_pool(const float* __restrict__ in,
                                                 float* __restrict__ out,
                                                 const int* __restrict__ ws) {
    const int nrows = ws[OFF_NROWS];
    const int ncols = ws[OFF_NCOLS];
    const int br = blockIdx.y;
    const int bc = blockIdx.x;
    if (br >= nrows || bc >= ncols) return;

    const int y0 = ws[OFF_ROWSTART + br];
    const int y1 = ws[OFF_ROWEND + br];
    const int x0 = ws[OFF_COLSTART + bc];
    const int x1 = ws[OFF_COLEND + bc];
    const int wdt = x1 - x0;

    const int tid = threadIdx.x;
    const int c = tid & 63;   // channel lane: coalesced 256B per (y,x)
    const int g = tid >> 6;   // pixel group 0..3

    float acc = 0.f;
    for (int y = y0; y < y1; ++y) {
        const float* rowp = in + ((size_t)(y * GW + x0)) * GC + c;
        for (int x = g; x < wdt; x += 4) acc += rowp[(size_t)x * GC];
    }

    __shared__ float sred[256];
    sred[tid] = acc;
    __syncthreads();
    if (g == 0) {
        float sum = sred[c] + sred[c + 64] + sred[c + 128] + sred[c + 192];
        float area = (float)((y1 - y0) * wdt);  // area >= 1 always
        sred[c] = sum / area;
    }
    __syncthreads();
    const float mval = sred[c];

    for (int y = y0; y < y1; ++y) {
        float* rowp = out + ((size_t)(y * GW + x0)) * GC + c;
        for (int x = g; x < wdt; x += 4) rowp[(size_t)x * GC] = mval;
    }
}

extern "C" void kernel_launch(void* const* d_in, const int* in_sizes, int n_in,
                              void* d_out, int out_size, void* d_ws, size_t ws_size,
                              hipStream_t stream) {
    const float* in  = (const float*)d_in[0];   // [1,768,768,64] fp32
    const int* hmask = (const int*)d_in[1];     // [1,768] int32
    const int* vmask = (const int*)d_in[2];     // [1,768] int32
    float* out = (float*)d_out;                 // [1,768,768,64] fp32
    int* ws = (int*)d_ws;

    seg_scan<<<2, GH, 0, stream>>>(hmask, vmask, ws);
    dim3 grid(MAXSEG, MAXSEG);
    cell_pool<<<grid, 256, 0, stream>>>(in, out, ws);
}

// Round 2
// 281.987 us; speedup vs baseline: 1.1099x; 1.1099x over previous
//
#include <hip/hip_runtime.h>

// GridPoolingLayer: per-cell mean pooling where cells are rectangles defined
// by rising edges of h_mask (rows) and v_mask (cols). H=W=768, C=64, fp32.
//
// R2: one WAVE per cell (persistent waves), float4 lanes.
//   lane = pg*16 + cq : pg = pixel group 0..3, cq = channel quad (4 floats).
//   Per wave-instruction: 4 pixels x 64 channels x 4B = 1 KB coalesced.
//   No LDS / no barriers in the hot loop; 2-step shfl_xor combines the
//   4 pixel-group partials. Fixed grid (graph-capture safe); waves stride
//   over the nrows*ncols real cells, so empty-block dispatch is eliminated.

#define GH 768
#define GW 768
#define GC 64
#define MAXSEG 385  // alternating mask gives 384 rising edges -> 385 segments

enum {
    OFF_ROWSTART = 0,
    OFF_ROWEND   = OFF_ROWSTART + MAXSEG,
    OFF_COLSTART = OFF_ROWEND + MAXSEG,
    OFF_COLEND   = OFF_COLSTART + MAXSEG,
    OFF_NROWS    = OFF_COLEND + MAXSEG,
    OFF_NCOLS    = OFF_NROWS + 1,
};

__global__ __launch_bounds__(768) void seg_scan(const int* __restrict__ h_mask,
                                                const int* __restrict__ v_mask,
                                                int* __restrict__ ws) {
    __shared__ int s[GH];
    const int i = threadIdx.x;
    const bool is_row = (blockIdx.x == 0);
    const int* m = is_row ? h_mask : v_mask;

    int mi = m[i];
    int rising = 0;
    if (i > 0) rising = (mi == 1 && m[i - 1] == 0) ? 1 : 0;  // rising[0] forced 0
    s[i] = rising;
    __syncthreads();

    for (int off = 1; off < GH; off <<= 1) {
        int add = (i >= off) ? s[i - off] : 0;
        __syncthreads();
        s[i] += add;
        __syncthreads();
    }

    const int seg  = s[i];
    const int segL = (i == 0)      ? -1 : s[i - 1];
    const int segR = (i == GH - 1) ? -2 : s[i + 1];

    int* start = ws + (is_row ? OFF_ROWSTART : OFF_COLSTART);
    int* end   = ws + (is_row ? OFF_ROWEND   : OFF_COLEND);
    if (seg != segL) start[seg] = i;
    if (seg != segR) end[seg]   = i + 1;
    if (i == GH - 1) ws[is_row ? OFF_NROWS : OFF_NCOLS] = seg + 1;
}

__global__ __launch_bounds__(256) void cell_pool(const float4* __restrict__ in,
                                                 float4* __restrict__ out,
                                                 const int* __restrict__ ws) {
    const int nrows  = ws[OFF_NROWS];
    const int ncols  = ws[OFF_NCOLS];
    const int ncells = nrows * ncols;

    const int wave   = blockIdx.x * 4 + (threadIdx.x >> 6);
    const int nwaves = gridDim.x * 4;
    const int lane   = threadIdx.x & 63;
    const int pg     = lane >> 4;   // pixel group within x-chunk of 4
    const int cq     = lane & 15;   // channel quad: floats 4*cq .. 4*cq+3

    for (int cell = wave; cell < ncells; cell += nwaves) {
        const int br = cell / ncols;
        const int bc = cell - br * ncols;
        const int y0 = ws[OFF_ROWSTART + br];
        const int y1 = ws[OFF_ROWEND + br];
        const int x0 = ws[OFF_COLSTART + bc];
        const int x1 = ws[OFF_COLEND + bc];

        float4 acc = make_float4(0.f, 0.f, 0.f, 0.f);
        for (int y = y0; y < y1; ++y) {
            const size_t rb = (size_t)(y * GW) * 16 + cq;
            for (int x = x0 + pg; x < x1; x += 4) {
                float4 v = in[rb + (size_t)x * 16];
                acc.x += v.x; acc.y += v.y; acc.z += v.z; acc.w += v.w;
            }
        }
        // combine the 4 pixel-group partials; all lanes end with the full sum
        #pragma unroll
        for (int msk = 16; msk < 64; msk <<= 1) {
            acc.x += __shfl_xor(acc.x, msk, 64);
            acc.y += __shfl_xor(acc.y, msk, 64);
            acc.z += __shfl_xor(acc.z, msk, 64);
            acc.w += __shfl_xor(acc.w, msk, 64);
        }
        const float area = (float)((y1 - y0) * (x1 - x0));  // >= 1 always
        float4 mean;
        mean.x = acc.x / area; mean.y = acc.y / area;
        mean.z = acc.z / area; mean.w = acc.w / area;

        for (int y = y0; y < y1; ++y) {
            const size_t rb = (size_t)(y * GW) * 16 + cq;
            for (int x = x0 + pg; x < x1; x += 4) {
                out[rb + (size_t)x * 16] = mean;
            }
        }
    }
}

extern "C" void kernel_launch(void* const* d_in, const int* in_sizes, int n_in,
                              void* d_out, int out_size, void* d_ws, size_t ws_size,
                              hipStream_t stream) {
    const float* in  = (const float*)d_in[0];   // [1,768,768,64] fp32
    const int* hmask = (const int*)d_in[1];     // [1,768] int32
    const int* vmask = (const int*)d_in[2];     // [1,768] int32
    float* out = (float*)d_out;                 // [1,768,768,64] fp32
    int* ws = (int*)d_ws;

    seg_scan<<<2, GH, 0, stream>>>(hmask, vmask, ws);
    // 2048 blocks x 4 waves = 8192 persistent waves (32 waves/CU at 256 CUs)
    cell_pool<<<2048, 256, 0, stream>>>((const float4*)in, (float4*)out, ws);
}